// Round 4
// baseline (529.776 us; speedup 1.0000x reference)
//
#include <hip/hip_runtime.h>
#include <hip/hip_bf16.h>

typedef __attribute__((ext_vector_type(8))) short short8;
typedef __attribute__((ext_vector_type(4))) float floatx4;

#define B_    4
#define S_    2048
#define EMB_  1024
#define NH_   16
#define HD_   64

// convert 8 consecutive fp32 -> 8 packed bf16
__device__ __forceinline__ short8 cvt8(const float* __restrict__ p) {
  const float4 u = *(const float4*)p;
  const float4 v = *(const float4*)(p + 4);
  __bf16 t[8] = {(__bf16)u.x, (__bf16)u.y, (__bf16)u.z, (__bf16)u.w,
                 (__bf16)v.x, (__bf16)v.y, (__bf16)v.z, (__bf16)v.w};
  return *(const short8*)t;
}

// C[M,1024] = A[M,1024] @ W[1024,1024]^T + bias.  A,W fp32; C written bf16.
// mode 0: out[(b*16+h)*S*64 + s*64 + d]   Q/K layout [B,H,S,D]
// mode 1: out[((b*16+h)*64+d)*S + s]      V^T layout [B,H,D,S] (packed 8B stores)
__global__ __launch_bounds__(256)
void gemm_x_kernel(const float* __restrict__ A, const float* __restrict__ W,
                   const float* __restrict__ bias, __bf16* __restrict__ out,
                   const int mode)
{
  __shared__ __attribute__((aligned(16))) __bf16 As[128 * 32];
  __shared__ __attribute__((aligned(16))) __bf16 Ws[128 * 32];
  const int tid  = threadIdx.x;
  const int wave = tid >> 6, lane = tid & 63;
  const int l15  = lane & 15, quad = lane >> 4;
  const int wm   = wave >> 1, wn = wave & 1;
  const int bm   = blockIdx.y * 128;
  const int bn   = blockIdx.x * 128;

  floatx4 acc[4][4];
#pragma unroll
  for (int i = 0; i < 4; ++i)
#pragma unroll
    for (int j = 0; j < 4; ++j) acc[i][j] = (floatx4){0.f, 0.f, 0.f, 0.f};

  const int srow = tid >> 2;          // 0..63
  const int scol = (tid & 3) << 3;    // 0,8,16,24
  const float* Ag = A + (size_t)(bm + srow) * 1024 + scol;
  const float* Wg = W + (size_t)(bn + srow) * 1024 + scol;
  __bf16* AsD = As + tid * 8;
  __bf16* WsD = Ws + tid * 8;

  for (int k0 = 0; k0 < 1024; k0 += 32) {
    const short8 a0 = cvt8(Ag + k0);
    const short8 a1 = cvt8(Ag + k0 + 64 * 1024);
    const short8 w0 = cvt8(Wg + k0);
    const short8 w1 = cvt8(Wg + k0 + 64 * 1024);
    __syncthreads();                     // prev iteration's fragment reads done
    *(short8*)AsD          = a0;
    *(short8*)(AsD + 2048) = a1;
    *(short8*)WsD          = w0;
    *(short8*)(WsD + 2048) = w1;
    __syncthreads();

    short8 af[4], wf[4];
#pragma unroll
    for (int mi = 0; mi < 4; ++mi)
      af[mi] = *(const short8*)(As + ((wm * 64 + mi * 16 + l15) << 5) + (quad << 3));
#pragma unroll
    for (int ni = 0; ni < 4; ++ni)
      wf[ni] = *(const short8*)(Ws + ((wn * 64 + ni * 16 + l15) << 5) + (quad << 3));
#pragma unroll
    for (int mi = 0; mi < 4; ++mi)
#pragma unroll
      for (int ni = 0; ni < 4; ++ni)
        acc[mi][ni] = __builtin_amdgcn_mfma_f32_16x16x32_bf16(af[mi], wf[ni], acc[mi][ni], 0, 0, 0);
  }

#pragma unroll
  for (int ni = 0; ni < 4; ++ni) {
    const int n = bn + wn * 64 + ni * 16 + l15;
    const float bvb = bias[n];
#pragma unroll
    for (int mi = 0; mi < 4; ++mi) {
      const int m0 = bm + wm * 64 + mi * 16 + quad * 4;
      floatx4 v = acc[mi][ni];
      const int b = m0 >> 11, s0 = m0 & 2047;
      const int h = n >> 6, d = n & 63;
      if (mode == 0) {
        const size_t base = (size_t)(b * 16 + h) * (S_ * 64) + d;
#pragma unroll
        for (int r = 0; r < 4; ++r)
          out[base + (size_t)(s0 + r) * 64] = (__bf16)(v[r] + bvb);
      } else {
        const size_t base = ((size_t)(b * 16 + h) * 64 + d) * S_ + s0;
        union { ushort4 u4; unsigned short u[4]; } pk;
#pragma unroll
        for (int r = 0; r < 4; ++r) {
          __bf16 hv = (__bf16)(v[r] + bvb);
          pk.u[r] = *(unsigned short*)&hv;
        }
        *(ushort4*)(out + base) = pk.u4;   // 8B aligned: s0 % 4 == 0
      }
    }
  }
}

// Final projection: A is attn output, bf16 in [B,H,S,D] layout; W,bias fp32;
// out fp32 row-major [M,1024].
__global__ __launch_bounds__(256)
void gemm_o_kernel(const __bf16* __restrict__ A, const float* __restrict__ W,
                   const float* __restrict__ bias, float* __restrict__ out)
{
  __shared__ __attribute__((aligned(16))) __bf16 As[128 * 32];
  __shared__ __attribute__((aligned(16))) __bf16 Ws[128 * 32];
  const int tid  = threadIdx.x;
  const int wave = tid >> 6, lane = tid & 63;
  const int l15  = lane & 15, quad = lane >> 4;
  const int wm   = wave >> 1, wn = wave & 1;
  const int bm   = blockIdx.y * 128;
  const int bn   = blockIdx.x * 128;

  floatx4 acc[4][4];
#pragma unroll
  for (int i = 0; i < 4; ++i)
#pragma unroll
    for (int j = 0; j < 4; ++j) acc[i][j] = (floatx4){0.f, 0.f, 0.f, 0.f};

  const int srow = tid >> 2;
  const int scol = (tid & 3) << 3;
  const float* Wg = W + (size_t)(bn + srow) * 1024 + scol;
  const int bb = bm >> 11;                 // batch (rows m = b*S + s)
  const int ss = (bm & 2047) + srow;       // seq
  __bf16* AsD = As + tid * 8;
  __bf16* WsD = Ws + tid * 8;

  for (int k0 = 0; k0 < 1024; k0 += 32) {
    const int c = k0 + scol, h = c >> 6, dd = c & 63;   // no head-crossing in 8 elems
    const __bf16* pa0 = A + (((size_t)(bb * 16 + h) * S_) + ss) * 64 + dd;
    const uint4  a0 = *(const uint4*)pa0;               // 8 bf16
    const uint4  a1 = *(const uint4*)(pa0 + 64 * 64);   // s -> s+64
    const short8 w0 = cvt8(Wg + k0);
    const short8 w1 = cvt8(Wg + k0 + 64 * 1024);
    __syncthreads();
    *(uint4*)AsD           = a0;
    *(uint4*)(AsD + 2048)  = a1;
    *(short8*)WsD          = w0;
    *(short8*)(WsD + 2048) = w1;
    __syncthreads();

    short8 af[4], wf[4];
#pragma unroll
    for (int mi = 0; mi < 4; ++mi)
      af[mi] = *(const short8*)(As + ((wm * 64 + mi * 16 + l15) << 5) + (quad << 3));
#pragma unroll
    for (int ni = 0; ni < 4; ++ni)
      wf[ni] = *(const short8*)(Ws + ((wn * 64 + ni * 16 + l15) << 5) + (quad << 3));
#pragma unroll
    for (int mi = 0; mi < 4; ++mi)
#pragma unroll
      for (int ni = 0; ni < 4; ++ni)
        acc[mi][ni] = __builtin_amdgcn_mfma_f32_16x16x32_bf16(af[mi], wf[ni], acc[mi][ni], 0, 0, 0);
  }

#pragma unroll
  for (int ni = 0; ni < 4; ++ni) {
    const int n = bn + wn * 64 + ni * 16 + l15;
    const float bvb = bias[n];
#pragma unroll
    for (int mi = 0; mi < 4; ++mi) {
      const int m0 = bm + wm * 64 + mi * 16 + quad * 4;
      floatx4 v = acc[mi][ni];
#pragma unroll
      for (int r = 0; r < 4; ++r)
        out[(size_t)(m0 + r) * 1024 + n] = v[r] + bvb;
    }
  }
}

// Flash attention, causal. Grid (qt=16, bh=64), 256 threads (4 waves).
// Q,K: [B,H,S,64] bf16; Vt: [B,H,64,S] bf16.
// Output written IN-PLACE over Q (each block owns its 128 rows exclusively).
__global__ __launch_bounds__(256)
void attn_kernel(__bf16* __restrict__ Q, const __bf16* __restrict__ K,
                 const __bf16* __restrict__ Vt)
{
  __shared__ __attribute__((aligned(16))) __bf16 Qs[128 * 72];
  __shared__ __attribute__((aligned(16))) __bf16 Ks[64 * 72];
  __shared__ __attribute__((aligned(16))) __bf16 Vs[64 * 72];
  __shared__ __attribute__((aligned(16))) __bf16 Ps[4][32 * 72];

  const int tid  = threadIdx.x;
  const int wave = tid >> 6, lane = tid & 63;
  const int l15  = lane & 15, quad = lane >> 4;
  const int qt   = blockIdx.x, bh = blockIdx.y;
  const size_t hb = (size_t)bh * (S_ * 64);
  const int q0 = qt * 128;
  const float MASKV = -1.0e30f;

  {  // stage Q tile [128][64] -> Qs[128][72]
    const int r = tid >> 3;
    const int c = (tid & 7) << 3;
#pragma unroll
    for (int p = 0; p < 4; ++p) {
      const int row = r + p * 32;
      *(uint4*)(&Qs[row * 72 + c]) = *(const uint4*)(Q + hb + (size_t)(q0 + row) * 64 + c);
    }
  }

  floatx4 oacc[2][4];
#pragma unroll
  for (int i = 0; i < 2; ++i)
#pragma unroll
    for (int j = 0; j < 4; ++j) oacc[i][j] = (floatx4){0.f, 0.f, 0.f, 0.f};
  float mst[2][4], lst[2][4];
#pragma unroll
  for (int i = 0; i < 2; ++i)
#pragma unroll
    for (int r = 0; r < 4; ++r) { mst[i][r] = MASKV; lst[i][r] = 0.f; }

  const int qw  = q0 + wave * 32;        // wave's first q row (seq-local)
  const int nkt = 2 * qt + 2;            // uniform across waves (barrier safety)
  const float SCL = 0.125f;              // 1/sqrt(64)

  for (int kt = 0; kt < nkt; ++kt) {
    __syncthreads();
    {  // stage K tile [64][64] and V^T tile [64][64]
      const int r = tid >> 3;
      const int c = (tid & 7) << 3;
#pragma unroll
      for (int p = 0; p < 2; ++p) {
        const int row = r + p * 32;
        *(uint4*)(&Ks[row * 72 + c]) = *(const uint4*)(K  + hb + (size_t)(kt * 64 + row) * 64 + c);
        *(uint4*)(&Vs[row * 72 + c]) = *(const uint4*)(Vt + hb + (size_t)row * S_ + kt * 64 + c);
      }
    }
    __syncthreads();

    floatx4 sacc[2][4];
#pragma unroll
    for (int i = 0; i < 2; ++i)
#pragma unroll
      for (int j = 0; j < 4; ++j) sacc[i][j] = (floatx4){0.f, 0.f, 0.f, 0.f};

#pragma unroll
    for (int kk = 0; kk < 2; ++kk) {   // d halves
      short8 aq[2], bk[4];
#pragma unroll
      for (int mi = 0; mi < 2; ++mi)
        aq[mi] = *(const short8*)(&Qs[(wave * 32 + mi * 16 + l15) * 72 + kk * 32 + quad * 8]);
#pragma unroll
      for (int ni = 0; ni < 4; ++ni)
        bk[ni] = *(const short8*)(&Ks[(ni * 16 + l15) * 72 + kk * 32 + quad * 8]);
#pragma unroll
      for (int mi = 0; mi < 2; ++mi)
#pragma unroll
        for (int ni = 0; ni < 4; ++ni)
          sacc[mi][ni] = __builtin_amdgcn_mfma_f32_16x16x32_bf16(aq[mi], bk[ni], sacc[mi][ni], 0, 0, 0);
    }

    // online softmax; C-layout: row = quad*4+reg, col = lane&15 (+16*ni)
    const int sc0 = kt * 64 + l15;
#pragma unroll
    for (int mi = 0; mi < 2; ++mi) {
      const int qrow = qw + mi * 16 + quad * 4;
#pragma unroll
      for (int r = 0; r < 4; ++r) {
        const int qg = qrow + r;
        float z[4];
        float tmax = MASKV;
#pragma unroll
        for (int ni = 0; ni < 4; ++ni) {
          float zz = sacc[mi][ni][r] * SCL;
          if (sc0 + ni * 16 > qg) zz = MASKV;   // causal: mask key > query
          z[ni] = zz;
          tmax = fmaxf(tmax, zz);
        }
        tmax = fmaxf(tmax, __shfl_xor(tmax, 1));
        tmax = fmaxf(tmax, __shfl_xor(tmax, 2));
        tmax = fmaxf(tmax, __shfl_xor(tmax, 4));
        tmax = fmaxf(tmax, __shfl_xor(tmax, 8));
        const float mold = mst[mi][r];
        const float mnew = fmaxf(mold, tmax);
        mst[mi][r] = mnew;
        const float alpha = __expf(mold - mnew);
        float rs = 0.f;
#pragma unroll
        for (int ni = 0; ni < 4; ++ni) {
          const float p = __expf(z[ni] - mnew);
          rs += p;
          Ps[wave][(mi * 16 + quad * 4 + r) * 72 + ni * 16 + l15] = (__bf16)p;
        }
        rs += __shfl_xor(rs, 1);
        rs += __shfl_xor(rs, 2);
        rs += __shfl_xor(rs, 4);
        rs += __shfl_xor(rs, 8);
        lst[mi][r] = lst[mi][r] * alpha + rs;
#pragma unroll
        for (int ni = 0; ni < 4; ++ni) oacc[mi][ni][r] *= alpha;
      }
    }

    __syncthreads();   // Ps writes visible before b128 fragment reads

    // O += P(32x64) @ V(64x64); A = Ps (per-wave), B = Vs
#pragma unroll
    for (int kk = 0; kk < 2; ++kk) {
      short8 ap[2], bv[4];
#pragma unroll
      for (int mi = 0; mi < 2; ++mi)
        ap[mi] = *(const short8*)(&Ps[wave][(mi * 16 + l15) * 72 + kk * 32 + quad * 8]);
#pragma unroll
      for (int ni = 0; ni < 4; ++ni)
        bv[ni] = *(const short8*)(&Vs[(ni * 16 + l15) * 72 + kk * 32 + quad * 8]);
#pragma unroll
      for (int mi = 0; mi < 2; ++mi)
#pragma unroll
        for (int ni = 0; ni < 4; ++ni)
          oacc[mi][ni] = __builtin_amdgcn_mfma_f32_16x16x32_bf16(ap[mi], bv[ni], oacc[mi][ni], 0, 0, 0);
    }
  }

  // epilogue: O /= l, write in-place over Q's own 128 rows ([B,H,S,D] layout)
#pragma unroll
  for (int mi = 0; mi < 2; ++mi) {
#pragma unroll
    for (int r = 0; r < 4; ++r) {
      const float inv = 1.0f / fmaxf(lst[mi][r], 1e-20f);
      const int qg = qw + mi * 16 + quad * 4 + r;
      const size_t rowb = hb + (size_t)qg * 64;
#pragma unroll
      for (int ni = 0; ni < 4; ++ni)
        Q[rowb + ni * 16 + l15] = (__bf16)(oacc[mi][ni][r] * inv);
    }
  }
}

extern "C" void kernel_launch(void* const* d_in, const int* in_sizes, int n_in,
                              void* d_out, int out_size, void* d_ws, size_t ws_size,
                              hipStream_t stream) {
  // Reference dtypes: ALL float32 (mask int32) — inputs are fp32, output fp32.
  const float* x  = (const float*)d_in[0];
  const float* Wq = (const float*)d_in[1];
  const float* bq = (const float*)d_in[2];
  const float* Wk = (const float*)d_in[3];
  const float* bk = (const float*)d_in[4];
  const float* Wv = (const float*)d_in[5];
  const float* bv = (const float*)d_in[6];
  const float* Wo = (const float*)d_in[7];
  const float* bo = (const float*)d_in[8];
  // d_in[9] = causal_mask (int32) — causality implemented analytically, unused.

  const size_t BUF = (size_t)B_ * NH_ * S_ * HD_;   // 8388608 bf16 = 16 MB
  __bf16* Qb = (__bf16*)d_ws;          // ws use: 16 MB (attn writes out in-place)
  __bf16* Kb = (__bf16*)d_out;         // d_out = 33.55 MB fp32 buffer reused as
  __bf16* Vb = (__bf16*)d_out + BUF;   // bf16 K + V^T scratch, consumed by attn
                                       // before final GEMM overwrites d_out.
  dim3 blk(256);
  dim3 gp(8, 64);     // N/128, M/128 for 8192x1024 GEMMs
  gemm_x_kernel<<<gp, blk, 0, stream>>>(x, Wq, bq, Qb, 0);
  gemm_x_kernel<<<gp, blk, 0, stream>>>(x, Wk, bk, Kb, 0);
  gemm_x_kernel<<<gp, blk, 0, stream>>>(x, Wv, bv, Vb, 1);
  attn_kernel<<<dim3(16, 64), blk, 0, stream>>>(Qb, Kb, Vb);
  // final projection: reads attn output (bf16 BHSD, in ws), writes fp32 d_out
  gemm_o_kernel<<<gp, blk, 0, stream>>>(Qb, Wo, bo, (float*)d_out);
}

// Round 5
// 354.848 us; speedup vs baseline: 1.4930x; 1.4930x over previous
//
#include <hip/hip_runtime.h>
#include <hip/hip_bf16.h>

typedef __attribute__((ext_vector_type(8))) short short8;
typedef __attribute__((ext_vector_type(4))) float floatx4;

#define B_    4
#define S_    2048
#define EMB_  1024
#define NH_   16
#define HD_   64

__device__ __forceinline__ void async_cp16(const void* g, void* l) {
  __builtin_amdgcn_global_load_lds(
      (const __attribute__((address_space(1))) unsigned int*)g,
      (__attribute__((address_space(3))) unsigned int*)l, 16, 0, 0);
}

__device__ __forceinline__ ushort4 cvt4(const float4 f) {
  __bf16 t[4] = {(__bf16)f.x, (__bf16)f.y, (__bf16)f.z, (__bf16)f.w};
  return *(const ushort4*)t;
}

// One-shot fp32 -> bf16 conversion of x, Wq|Wk|Wv (stacked into Wcat), Wo,
// plus fp32 bias packing bq|bk|bv -> bcat. 4 elems/thread.
__global__ __launch_bounds__(256)
void cvt_kernel(const float* __restrict__ x,
                const float* __restrict__ wq, const float* __restrict__ wk,
                const float* __restrict__ wv, const float* __restrict__ wo,
                const float* __restrict__ bq, const float* __restrict__ bk,
                const float* __restrict__ bv,
                __bf16* __restrict__ xb, __bf16* __restrict__ Wcat,
                __bf16* __restrict__ Wob, float* __restrict__ bcat)
{
  const int NX4 = 2097152;   // 8388608/4
  const int NW4 = 262144;    // 1048576/4
  int g = blockIdx.x * 256 + threadIdx.x;
  if (g < NX4) {
    *(ushort4*)(xb + (size_t)g * 4) = cvt4(*(const float4*)(x + (size_t)g * 4));
    return;
  }
  g -= NX4;
  if (g < 3 * NW4) {   // Wcat = [Wq; Wk; Wv] row-stacked
    const float* src = (g < NW4) ? wq : (g < 2 * NW4) ? wk : wv;
    const int gg = (g < NW4) ? g : (g < 2 * NW4) ? g - NW4 : g - 2 * NW4;
    *(ushort4*)(Wcat + (size_t)g * 4) = cvt4(*(const float4*)(src + (size_t)gg * 4));
    return;
  }
  g -= 3 * NW4;
  if (g < NW4) {
    *(ushort4*)(Wob + (size_t)g * 4) = cvt4(*(const float4*)(wo + (size_t)g * 4));
    return;
  }
  g -= NW4;
  if (g < 768) {       // bcat = [bq; bk; bv] fp32
    const float* src = (g < 256) ? bq : (g < 512) ? bk : bv;
    *(float4*)(bcat + (size_t)g * 4) = *(const float4*)(src + (size_t)(g & 255) * 4);
  }
}

// Fused QKV: C[8192,3072] = xb @ Wcat^T + bcat, all bf16, global_load_lds staging.
// n<1024 -> Q (scaled by SCL*log2e) BHSD; n<2048 -> K BHSD; else -> V^T BHDS.
__global__ __launch_bounds__(256)
void gemm_qkv_kernel(const __bf16* __restrict__ A, const __bf16* __restrict__ W,
                     const float* __restrict__ bcat,
                     __bf16* __restrict__ Qb, __bf16* __restrict__ Kb,
                     __bf16* __restrict__ Vb)
{
  __shared__ __attribute__((aligned(16))) __bf16 As[128 * 32];
  __shared__ __attribute__((aligned(16))) __bf16 Ws[128 * 32];
  const int tid  = threadIdx.x;
  const int wave = tid >> 6, lane = tid & 63;
  const int l15  = lane & 15, quad = lane >> 4;
  const int wm   = wave >> 1, wn = wave & 1;
  const int bm   = blockIdx.y * 128;
  const int bn   = blockIdx.x * 128;        // 0..2944
  const int widx = bn >> 10;                // 0=Q 1=K 2=V (block-uniform)
  const float QS = 0.180336880f;            // (1/sqrt(64)) * log2(e)

  floatx4 acc[4][4];
#pragma unroll
  for (int i = 0; i < 4; ++i)
#pragma unroll
    for (int j = 0; j < 4; ++j) acc[i][j] = (floatx4){0.f, 0.f, 0.f, 0.f};

  const int srow = tid >> 2;          // 0..63
  const int scol = (tid & 3) << 3;    // 0,8,16,24
  const __bf16* Ag = A + (size_t)(bm + srow) * 1024 + scol;
  const __bf16* Wg = W + (size_t)(bn + srow) * 1024 + scol;
  __bf16* AsD = As + tid * 8;
  __bf16* WsD = Ws + tid * 8;

  for (int k0 = 0; k0 < 1024; k0 += 32) {
    __syncthreads();
    async_cp16(Ag + k0,             AsD);
    async_cp16(Ag + k0 + 64 * 1024, AsD + 2048);
    async_cp16(Wg + k0,             WsD);
    async_cp16(Wg + k0 + 64 * 1024, WsD + 2048);
    __syncthreads();
    short8 af[4], wf[4];
#pragma unroll
    for (int mi = 0; mi < 4; ++mi)
      af[mi] = *(const short8*)(As + ((wm * 64 + mi * 16 + l15) << 5) + (quad << 3));
#pragma unroll
    for (int ni = 0; ni < 4; ++ni)
      wf[ni] = *(const short8*)(Ws + ((wn * 64 + ni * 16 + l15) << 5) + (quad << 3));
#pragma unroll
    for (int mi = 0; mi < 4; ++mi)
#pragma unroll
      for (int ni = 0; ni < 4; ++ni)
        acc[mi][ni] = __builtin_amdgcn_mfma_f32_16x16x32_bf16(af[mi], wf[ni], acc[mi][ni], 0, 0, 0);
  }

#pragma unroll
  for (int ni = 0; ni < 4; ++ni) {
    const int n  = bn + wn * 64 + ni * 16 + l15;
    const float bvb = bcat[n];
    const int np = n & 1023;
    const int h = np >> 6, d = np & 63;
#pragma unroll
    for (int mi = 0; mi < 4; ++mi) {
      const int m0 = bm + wm * 64 + mi * 16 + quad * 4;
      const int b = m0 >> 11, s0 = m0 & 2047;
      floatx4 v = acc[mi][ni];
      if (widx == 0) {
        const size_t base = (size_t)(b * 16 + h) * (S_ * 64) + d;
#pragma unroll
        for (int r = 0; r < 4; ++r)
          Qb[base + (size_t)(s0 + r) * 64] = (__bf16)((v[r] + bvb) * QS);
      } else if (widx == 1) {
        const size_t base = (size_t)(b * 16 + h) * (S_ * 64) + d;
#pragma unroll
        for (int r = 0; r < 4; ++r)
          Kb[base + (size_t)(s0 + r) * 64] = (__bf16)(v[r] + bvb);
      } else {
        const size_t base = ((size_t)(b * 16 + h) * 64 + d) * S_ + s0;
        union { ushort4 u4; unsigned short u[4]; } pk;
#pragma unroll
        for (int r = 0; r < 4; ++r) {
          __bf16 hv = (__bf16)(v[r] + bvb);
          pk.u[r] = *(unsigned short*)&hv;
        }
        *(ushort4*)(Vb + base) = pk.u4;    // 8B aligned: s0 % 4 == 0
      }
    }
  }
}

// Flash attention, causal, exp2-domain (Q pre-scaled by SCL*log2e).
// Grid (8, 64): block pairs q-tiles {qtA, 15-qtA} -> 34 k-tiles/block, balanced.
// Q,K: [B,H,S,64]; Vt: [B,H,64,S]. Output IN-PLACE over Q (block-owned rows).
__global__ __launch_bounds__(256)
void attn_kernel(__bf16* __restrict__ Q, const __bf16* __restrict__ K,
                 const __bf16* __restrict__ Vt)
{
  __shared__ __attribute__((aligned(16))) __bf16 Qs[128 * 72];
  __shared__ __attribute__((aligned(16))) __bf16 Ks[64 * 72];
  __shared__ __attribute__((aligned(16))) __bf16 Vs[64 * 72];
  __shared__ __attribute__((aligned(16))) __bf16 Ps[4][32 * 72];

  const int tid  = threadIdx.x;
  const int wave = tid >> 6, lane = tid & 63;
  const int l15  = lane & 15, quad = lane >> 4;
  const int qtA  = blockIdx.x, bh = blockIdx.y;
  const size_t hb = (size_t)bh * (S_ * 64);
  const float MASKV = -1.0e30f;

  for (int qsel = 0; qsel < 2; ++qsel) {
    const int qt = qsel ? (15 - qtA) : qtA;
    const int q0 = qt * 128;

    {  // stage Q tile [128][64] -> Qs[128][72] (safe: prior reads all barriered)
      const int r = tid >> 3;
      const int c = (tid & 7) << 3;
#pragma unroll
      for (int p = 0; p < 4; ++p) {
        const int row = r + p * 32;
        *(uint4*)(&Qs[row * 72 + c]) = *(const uint4*)(Q + hb + (size_t)(q0 + row) * 64 + c);
      }
    }

    floatx4 oacc[2][4];
#pragma unroll
    for (int i = 0; i < 2; ++i)
#pragma unroll
      for (int j = 0; j < 4; ++j) oacc[i][j] = (floatx4){0.f, 0.f, 0.f, 0.f};
    float mst[2][4], lst[2][4];
#pragma unroll
    for (int i = 0; i < 2; ++i)
#pragma unroll
      for (int r = 0; r < 4; ++r) { mst[i][r] = MASKV; lst[i][r] = 0.f; }

    const int qw  = q0 + wave * 32;
    const int nkt = 2 * qt + 2;

    for (int kt = 0; kt < nkt; ++kt) {
      __syncthreads();
      {  // stage K tile [64][64] and V^T tile [64][64]
        const int r = tid >> 3;
        const int c = (tid & 7) << 3;
#pragma unroll
        for (int p = 0; p < 2; ++p) {
          const int row = r + p * 32;
          *(uint4*)(&Ks[row * 72 + c]) = *(const uint4*)(K  + hb + (size_t)(kt * 64 + row) * 64 + c);
          *(uint4*)(&Vs[row * 72 + c]) = *(const uint4*)(Vt + hb + (size_t)row * S_ + kt * 64 + c);
        }
      }
      __syncthreads();

      floatx4 sacc[2][4];
#pragma unroll
      for (int i = 0; i < 2; ++i)
#pragma unroll
        for (int j = 0; j < 4; ++j) sacc[i][j] = (floatx4){0.f, 0.f, 0.f, 0.f};

#pragma unroll
      for (int kk = 0; kk < 2; ++kk) {
        short8 aq[2], bk[4];
#pragma unroll
        for (int mi = 0; mi < 2; ++mi)
          aq[mi] = *(const short8*)(&Qs[(wave * 32 + mi * 16 + l15) * 72 + kk * 32 + quad * 8]);
#pragma unroll
        for (int ni = 0; ni < 4; ++ni)
          bk[ni] = *(const short8*)(&Ks[(ni * 16 + l15) * 72 + kk * 32 + quad * 8]);
#pragma unroll
        for (int mi = 0; mi < 2; ++mi)
#pragma unroll
          for (int ni = 0; ni < 4; ++ni)
            sacc[mi][ni] = __builtin_amdgcn_mfma_f32_16x16x32_bf16(aq[mi], bk[ni], sacc[mi][ni], 0, 0, 0);
      }

      // online softmax in exp2 domain (scores already * SCL*log2e via Q)
      const int sc0 = kt * 64 + l15;
#pragma unroll
      for (int mi = 0; mi < 2; ++mi) {
        const int qrow = qw + mi * 16 + quad * 4;
#pragma unroll
        for (int r = 0; r < 4; ++r) {
          const int qg = qrow + r;
          float z[4];
          float tmax = MASKV;
#pragma unroll
          for (int ni = 0; ni < 4; ++ni) {
            float zz = sacc[mi][ni][r];
            if (sc0 + ni * 16 > qg) zz = MASKV;   // causal: mask key > query
            z[ni] = zz;
            tmax = fmaxf(tmax, zz);
          }
          tmax = fmaxf(tmax, __shfl_xor(tmax, 1));
          tmax = fmaxf(tmax, __shfl_xor(tmax, 2));
          tmax = fmaxf(tmax, __shfl_xor(tmax, 4));
          tmax = fmaxf(tmax, __shfl_xor(tmax, 8));
          const float mold = mst[mi][r];
          const float mnew = fmaxf(mold, tmax);
          mst[mi][r] = mnew;
          const float alpha = exp2f(mold - mnew);
          float rs = 0.f;
#pragma unroll
          for (int ni = 0; ni < 4; ++ni) {
            const float p = exp2f(z[ni] - mnew);
            rs += p;
            Ps[wave][(mi * 16 + quad * 4 + r) * 72 + ni * 16 + l15] = (__bf16)p;
          }
          rs += __shfl_xor(rs, 1);
          rs += __shfl_xor(rs, 2);
          rs += __shfl_xor(rs, 4);
          rs += __shfl_xor(rs, 8);
          lst[mi][r] = lst[mi][r] * alpha + rs;
#pragma unroll
          for (int ni = 0; ni < 4; ++ni) oacc[mi][ni][r] *= alpha;
        }
      }

      __syncthreads();   // Ps writes visible before b128 fragment reads

      // O += P(32x64) @ V(64x64)
#pragma unroll
      for (int kk = 0; kk < 2; ++kk) {
        short8 ap[2], bv[4];
#pragma unroll
        for (int mi = 0; mi < 2; ++mi)
          ap[mi] = *(const short8*)(&Ps[wave][(mi * 16 + l15) * 72 + kk * 32 + quad * 8]);
#pragma unroll
        for (int ni = 0; ni < 4; ++ni)
          bv[ni] = *(const short8*)(&Vs[(ni * 16 + l15) * 72 + kk * 32 + quad * 8]);
#pragma unroll
        for (int mi = 0; mi < 2; ++mi)
#pragma unroll
          for (int ni = 0; ni < 4; ++ni)
            oacc[mi][ni] = __builtin_amdgcn_mfma_f32_16x16x32_bf16(ap[mi], bv[ni], oacc[mi][ni], 0, 0, 0);
      }
    }

    // epilogue: O /= l, write in-place over this q-tile's own rows (BHSD)
#pragma unroll
    for (int mi = 0; mi < 2; ++mi) {
#pragma unroll
      for (int r = 0; r < 4; ++r) {
        const float inv = 1.0f / fmaxf(lst[mi][r], 1e-20f);
        const int qg = qw + mi * 16 + quad * 4 + r;
        const size_t rowb = hb + (size_t)qg * 64;
#pragma unroll
        for (int ni = 0; ni < 4; ++ni)
          Q[rowb + ni * 16 + l15] = (__bf16)(oacc[mi][ni][r] * inv);
      }
    }
  }
}

// Final projection: A = attn output (bf16, BHSD gather), W = Wob bf16,
// bias fp32, out fp32 row-major. global_load_lds staging.
__global__ __launch_bounds__(256)
void gemm_o_kernel(const __bf16* __restrict__ A, const __bf16* __restrict__ W,
                   const float* __restrict__ bias, float* __restrict__ out)
{
  __shared__ __attribute__((aligned(16))) __bf16 As[128 * 32];
  __shared__ __attribute__((aligned(16))) __bf16 Ws[128 * 32];
  const int tid  = threadIdx.x;
  const int wave = tid >> 6, lane = tid & 63;
  const int l15  = lane & 15, quad = lane >> 4;
  const int wm   = wave >> 1, wn = wave & 1;
  const int bm   = blockIdx.y * 128;
  const int bn   = blockIdx.x * 128;

  floatx4 acc[4][4];
#pragma unroll
  for (int i = 0; i < 4; ++i)
#pragma unroll
    for (int j = 0; j < 4; ++j) acc[i][j] = (floatx4){0.f, 0.f, 0.f, 0.f};

  const int srow = tid >> 2;
  const int scol = (tid & 3) << 3;
  const __bf16* Wg = W + (size_t)(bn + srow) * 1024 + scol;
  const int bb = bm >> 11;                 // batch
  const int ss = (bm & 2047) + srow;       // seq
  __bf16* AsD = As + tid * 8;
  __bf16* WsD = Ws + tid * 8;

  for (int k0 = 0; k0 < 1024; k0 += 32) {
    const int c = k0 + scol, h = c >> 6, dd = c & 63;  // 8 elems never cross a head
    const __bf16* pa0 = A + (((size_t)(bb * 16 + h) * S_) + ss) * 64 + dd;
    __syncthreads();
    async_cp16(pa0,           AsD);
    async_cp16(pa0 + 64 * 64, AsD + 2048);             // s -> s+64
    async_cp16(Wg + k0,             WsD);
    async_cp16(Wg + k0 + 64 * 1024, WsD + 2048);
    __syncthreads();

    short8 af[4], wf[4];
#pragma unroll
    for (int mi = 0; mi < 4; ++mi)
      af[mi] = *(const short8*)(As + ((wm * 64 + mi * 16 + l15) << 5) + (quad << 3));
#pragma unroll
    for (int ni = 0; ni < 4; ++ni)
      wf[ni] = *(const short8*)(Ws + ((wn * 64 + ni * 16 + l15) << 5) + (quad << 3));
#pragma unroll
    for (int mi = 0; mi < 4; ++mi)
#pragma unroll
      for (int ni = 0; ni < 4; ++ni)
        acc[mi][ni] = __builtin_amdgcn_mfma_f32_16x16x32_bf16(af[mi], wf[ni], acc[mi][ni], 0, 0, 0);
  }

#pragma unroll
  for (int ni = 0; ni < 4; ++ni) {
    const int n = bn + wn * 64 + ni * 16 + l15;
    const float bvb = bias[n];
#pragma unroll
    for (int mi = 0; mi < 4; ++mi) {
      const int m0 = bm + wm * 64 + mi * 16 + quad * 4;
      floatx4 v = acc[mi][ni];
#pragma unroll
      for (int r = 0; r < 4; ++r)
        out[(size_t)(m0 + r) * 1024 + n] = v[r] + bvb;
    }
  }
}

extern "C" void kernel_launch(void* const* d_in, const int* in_sizes, int n_in,
                              void* d_out, int out_size, void* d_ws, size_t ws_size,
                              hipStream_t stream) {
  const float* x  = (const float*)d_in[0];
  const float* Wq = (const float*)d_in[1];
  const float* bq = (const float*)d_in[2];
  const float* Wk = (const float*)d_in[3];
  const float* bk = (const float*)d_in[4];
  const float* Wv = (const float*)d_in[5];
  const float* bv = (const float*)d_in[6];
  const float* Wo = (const float*)d_in[7];
  const float* bo = (const float*)d_in[8];
  // d_in[9] = causal_mask (int32) — causality implemented analytically, unused.

  const size_t BUF = (size_t)B_ * NH_ * S_ * HD_;   // 8388608 elems
  __bf16* ws   = (__bf16*)d_ws;                     // ws usage: ~42 MB
  __bf16* xb   = ws;                                // 8388608  (16.8 MB)
  __bf16* Wcat = ws + 8388608;                      // 3145728  (6 MB)
  __bf16* Wob  = ws + 11534336;                     // 1048576  (2 MB)
  __bf16* Qb   = ws + 12582912;                     // 8388608  (16.8 MB)
  float*  bcat = (float*)(ws + 20971520);           // 3072 fp32 (12 KB)
  __bf16* Kb   = (__bf16*)d_out;                    // d_out reused as K+V^T
  __bf16* Vb   = (__bf16*)d_out + BUF;              // scratch until attn done

  dim3 blk(256);
  cvt_kernel<<<12291, blk, 0, stream>>>(x, Wq, Wk, Wv, Wo, bq, bk, bv,
                                        xb, Wcat, Wob, bcat);
  gemm_qkv_kernel<<<dim3(24, 64), blk, 0, stream>>>(xb, Wcat, bcat, Qb, Kb, Vb);
  attn_kernel<<<dim3(8, 64), blk, 0, stream>>>(Qb, Kb, Vb);
  gemm_o_kernel<<<dim3(8, 64), blk, 0, stream>>>(Qb, Wob, bo, (float*)d_out);
}

// Round 6
// 308.276 us; speedup vs baseline: 1.7185x; 1.1511x over previous
//
#include <hip/hip_runtime.h>
#include <hip/hip_bf16.h>

typedef __attribute__((ext_vector_type(8))) short short8;
typedef __attribute__((ext_vector_type(4))) float floatx4;

#define B_    4
#define S_    2048
#define EMB_  1024
#define NH_   16
#define HD_   64

#if __has_builtin(__builtin_amdgcn_exp2f)
#define EXP2F(x) __builtin_amdgcn_exp2f(x)
#else
#define EXP2F(x) exp2f(x)
#endif

__device__ __forceinline__ void async_cp16(const void* g, void* l) {
  __builtin_amdgcn_global_load_lds(
      (const __attribute__((address_space(1))) unsigned int*)g,
      (__attribute__((address_space(3))) unsigned int*)l, 16, 0, 0);
}

__device__ __forceinline__ ushort4 cvt4(const float4 f) {
  __bf16 t[4] = {(__bf16)f.x, (__bf16)f.y, (__bf16)f.z, (__bf16)f.w};
  return *(const ushort4*)t;
}

// One-shot fp32 -> bf16 conversion of x, Wq|Wk|Wv (stacked into Wcat), Wo,
// plus fp32 bias packing bq|bk|bv -> bcat. 4 elems/thread.
__global__ __launch_bounds__(256)
void cvt_kernel(const float* __restrict__ x,
                const float* __restrict__ wq, const float* __restrict__ wk,
                const float* __restrict__ wv, const float* __restrict__ wo,
                const float* __restrict__ bq, const float* __restrict__ bk,
                const float* __restrict__ bv,
                __bf16* __restrict__ xb, __bf16* __restrict__ Wcat,
                __bf16* __restrict__ Wob, float* __restrict__ bcat)
{
  const int NX4 = 2097152;   // 8388608/4
  const int NW4 = 262144;    // 1048576/4
  int g = blockIdx.x * 256 + threadIdx.x;
  if (g < NX4) {
    *(ushort4*)(xb + (size_t)g * 4) = cvt4(*(const float4*)(x + (size_t)g * 4));
    return;
  }
  g -= NX4;
  if (g < 3 * NW4) {   // Wcat = [Wq; Wk; Wv] row-stacked
    const float* src = (g < NW4) ? wq : (g < 2 * NW4) ? wk : wv;
    const int gg = (g < NW4) ? g : (g < 2 * NW4) ? g - NW4 : g - 2 * NW4;
    *(ushort4*)(Wcat + (size_t)g * 4) = cvt4(*(const float4*)(src + (size_t)gg * 4));
    return;
  }
  g -= 3 * NW4;
  if (g < NW4) {
    *(ushort4*)(Wob + (size_t)g * 4) = cvt4(*(const float4*)(wo + (size_t)g * 4));
    return;
  }
  g -= NW4;
  if (g < 768) {       // bcat = [bq; bk; bv] fp32
    const float* src = (g < 256) ? bq : (g < 512) ? bk : bv;
    *(float4*)(bcat + (size_t)g * 4) = *(const float4*)(src + (size_t)(g & 255) * 4);
  }
}

// Fused QKV: C[8192,3072] = xb @ Wcat^T + bcat, all bf16, global_load_lds staging.
// n<1024 -> Q (scaled by SCL*log2e) BHSD; n<2048 -> K BHSD; else -> V^T BHDS.
__global__ __launch_bounds__(256)
void gemm_qkv_kernel(const __bf16* __restrict__ A, const __bf16* __restrict__ W,
                     const float* __restrict__ bcat,
                     __bf16* __restrict__ Qb, __bf16* __restrict__ Kb,
                     __bf16* __restrict__ Vb)
{
  __shared__ __attribute__((aligned(16))) __bf16 As[128 * 32];
  __shared__ __attribute__((aligned(16))) __bf16 Ws[128 * 32];
  const int tid  = threadIdx.x;
  const int wave = tid >> 6, lane = tid & 63;
  const int l15  = lane & 15, quad = lane >> 4;
  const int wm   = wave >> 1, wn = wave & 1;
  const int bm   = blockIdx.y * 128;
  const int bn   = blockIdx.x * 128;        // 0..2944
  const int widx = bn >> 10;                // 0=Q 1=K 2=V (block-uniform)
  const float QS = 0.180336880f;            // (1/sqrt(64)) * log2(e)

  floatx4 acc[4][4];
#pragma unroll
  for (int i = 0; i < 4; ++i)
#pragma unroll
    for (int j = 0; j < 4; ++j) acc[i][j] = (floatx4){0.f, 0.f, 0.f, 0.f};

  const int srow = tid >> 2;          // 0..63
  const int scol = (tid & 3) << 3;    // 0,8,16,24
  const __bf16* Ag = A + (size_t)(bm + srow) * 1024 + scol;
  const __bf16* Wg = W + (size_t)(bn + srow) * 1024 + scol;
  __bf16* AsD = As + tid * 8;
  __bf16* WsD = Ws + tid * 8;

  for (int k0 = 0; k0 < 1024; k0 += 32) {
    __syncthreads();
    async_cp16(Ag + k0,             AsD);
    async_cp16(Ag + k0 + 64 * 1024, AsD + 2048);
    async_cp16(Wg + k0,             WsD);
    async_cp16(Wg + k0 + 64 * 1024, WsD + 2048);
    __syncthreads();
    short8 af[4], wf[4];
#pragma unroll
    for (int mi = 0; mi < 4; ++mi)
      af[mi] = *(const short8*)(As + ((wm * 64 + mi * 16 + l15) << 5) + (quad << 3));
#pragma unroll
    for (int ni = 0; ni < 4; ++ni)
      wf[ni] = *(const short8*)(Ws + ((wn * 64 + ni * 16 + l15) << 5) + (quad << 3));
#pragma unroll
    for (int mi = 0; mi < 4; ++mi)
#pragma unroll
      for (int ni = 0; ni < 4; ++ni)
        acc[mi][ni] = __builtin_amdgcn_mfma_f32_16x16x32_bf16(af[mi], wf[ni], acc[mi][ni], 0, 0, 0);
  }

#pragma unroll
  for (int ni = 0; ni < 4; ++ni) {
    const int n  = bn + wn * 64 + ni * 16 + l15;
    const float bvb = bcat[n];
    const int np = n & 1023;
    const int h = np >> 6, d = np & 63;
#pragma unroll
    for (int mi = 0; mi < 4; ++mi) {
      const int m0 = bm + wm * 64 + mi * 16 + quad * 4;
      const int b = m0 >> 11, s0 = m0 & 2047;
      floatx4 v = acc[mi][ni];
      if (widx == 0) {
        const size_t base = (size_t)(b * 16 + h) * (S_ * 64) + d;
#pragma unroll
        for (int r = 0; r < 4; ++r)
          Qb[base + (size_t)(s0 + r) * 64] = (__bf16)((v[r] + bvb) * QS);
      } else if (widx == 1) {
        const size_t base = (size_t)(b * 16 + h) * (S_ * 64) + d;
#pragma unroll
        for (int r = 0; r < 4; ++r)
          Kb[base + (size_t)(s0 + r) * 64] = (__bf16)(v[r] + bvb);
      } else {
        const size_t base = ((size_t)(b * 16 + h) * 64 + d) * S_ + s0;
        union { ushort4 u4; unsigned short u[4]; } pk;
#pragma unroll
        for (int r = 0; r < 4; ++r) {
          __bf16 hv = (__bf16)(v[r] + bvb);
          pk.u[r] = *(unsigned short*)&hv;
        }
        *(ushort4*)(Vb + base) = pk.u4;    // 8B aligned: s0 % 4 == 0
      }
    }
  }
}

// Flash attention, causal, exp2-domain (Q pre-scaled by SCL*log2e).
// Grid (16, 64): block pairs 64-row q-tiles {qtA, 31-qtA} -> 33 k-tiles, balanced.
// Each wave owns 16 q-rows; Q fragments in registers (no Qs LDS).
// l computed via MFMA ones-column (Vs row 64 = ones, rows 65..79 = 0).
// Output IN-PLACE over Q (block-owned rows).
__global__ __launch_bounds__(256, 4)
void attn_kernel(__bf16* __restrict__ Q, const __bf16* __restrict__ K,
                 const __bf16* __restrict__ Vt)
{
  __shared__ __attribute__((aligned(16))) __bf16 Ks[64 * 72];
  __shared__ __attribute__((aligned(16))) __bf16 Vs[80 * 72];
  __shared__ __attribute__((aligned(16))) __bf16 Ps[4][16 * 72];

  const int tid  = threadIdx.x;
  const int wave = tid >> 6, lane = tid & 63;
  const int l15  = lane & 15, quad = lane >> 4;
  const int qtA  = blockIdx.x, bh = blockIdx.y;
  const size_t hb = (size_t)bh * (S_ * 64);
  const float MASKV = -1.0e30f;

  // one-time init: Vs row 64 = ones (l-column), rows 65..79 = zeros
  for (int idx = tid; idx < 16 * 72; idx += 256)
    Vs[64 * 72 + idx] = (idx < 72) ? (__bf16)1.0f : (__bf16)0.0f;

  for (int qsel = 0; qsel < 2; ++qsel) {
    const int qt = qsel ? (31 - qtA) : qtA;
    const int q0 = qt * 64;
    const int qw = q0 + wave * 16;          // wave's first q row

    // Q fragments in registers: A[m=l15][k=kk*32+quad*8+j], rows qw..qw+15
    short8 aq[2];
#pragma unroll
    for (int kk = 0; kk < 2; ++kk)
      aq[kk] = *(const short8*)(Q + hb + (size_t)(qw + l15) * 64 + kk * 32 + quad * 8);

    floatx4 oacc[4];
#pragma unroll
    for (int j = 0; j < 4; ++j) oacc[j] = (floatx4){0.f, 0.f, 0.f, 0.f};
    floatx4 lacc = (floatx4){0.f, 0.f, 0.f, 0.f};
    float mst[4];
#pragma unroll
    for (int r = 0; r < 4; ++r) mst[r] = MASKV;

    for (int kt = 0; kt <= qt; ++kt) {
      __syncthreads();
      {  // stage K tile [64][64] and V^T tile [64][64] (rows 0..63 of Vs)
        const int r = tid >> 3;
        const int c = (tid & 7) << 3;
#pragma unroll
        for (int p = 0; p < 2; ++p) {
          const int row = r + p * 32;
          *(uint4*)(&Ks[row * 72 + c]) = *(const uint4*)(K  + hb + (size_t)(kt * 64 + row) * 64 + c);
          *(uint4*)(&Vs[row * 72 + c]) = *(const uint4*)(Vt + hb + (size_t)row * S_ + kt * 64 + c);
        }
      }
      __syncthreads();

      // S = Q K^T (pre-scaled by SCL*log2e)
      floatx4 sacc[4];
#pragma unroll
      for (int j = 0; j < 4; ++j) sacc[j] = (floatx4){0.f, 0.f, 0.f, 0.f};
#pragma unroll
      for (int kk = 0; kk < 2; ++kk) {
        short8 bk[4];
#pragma unroll
        for (int ni = 0; ni < 4; ++ni)
          bk[ni] = *(const short8*)(&Ks[(ni * 16 + l15) * 72 + kk * 32 + quad * 8]);
#pragma unroll
        for (int ni = 0; ni < 4; ++ni)
          sacc[ni] = __builtin_amdgcn_mfma_f32_16x16x32_bf16(aq[kk], bk[ni], sacc[ni], 0, 0, 0);
      }

      // online softmax (exp2 domain). Mask only on the diagonal tile.
      const bool needmask = (kt == qt);
      const int sc0 = kt * 64 + l15;
#pragma unroll
      for (int r = 0; r < 4; ++r) {
        const int qg = qw + quad * 4 + r;
        float z[4];
        if (needmask) {
#pragma unroll
          for (int ni = 0; ni < 4; ++ni) {
            float zz = sacc[ni][r];
            if (sc0 + ni * 16 > qg) zz = MASKV;   // causal: mask key > query
            z[ni] = zz;
          }
        } else {
#pragma unroll
          for (int ni = 0; ni < 4; ++ni) z[ni] = sacc[ni][r];
        }
        float tmax = fmaxf(fmaxf(z[0], z[1]), fmaxf(z[2], z[3]));
        tmax = fmaxf(tmax, __shfl_xor(tmax, 1));
        tmax = fmaxf(tmax, __shfl_xor(tmax, 2));
        tmax = fmaxf(tmax, __shfl_xor(tmax, 4));
        tmax = fmaxf(tmax, __shfl_xor(tmax, 8));
        const float mold = mst[r];
        const float mnew = fmaxf(mold, tmax);
        mst[r] = mnew;
        const float alpha = EXP2F(mold - mnew);
#pragma unroll
        for (int ni = 0; ni < 4; ++ni) {
          const float p = EXP2F(z[ni] - mnew);
          Ps[wave][(quad * 4 + r) * 72 + ni * 16 + l15] = (__bf16)p;
        }
#pragma unroll
        for (int ni = 0; ni < 4; ++ni) oacc[ni][r] *= alpha;
        lacc[r] *= alpha;
      }

      __syncthreads();   // Ps writes visible before b128 fragment reads

      // O += P(16x64) @ V(64x64); l += P @ ones  (Vs row 64)
#pragma unroll
      for (int kk = 0; kk < 2; ++kk) {
        const short8 ap = *(const short8*)(&Ps[wave][l15 * 72 + kk * 32 + quad * 8]);
        short8 bv[4];
#pragma unroll
        for (int ni = 0; ni < 4; ++ni)
          bv[ni] = *(const short8*)(&Vs[(ni * 16 + l15) * 72 + kk * 32 + quad * 8]);
        const short8 bl = *(const short8*)(&Vs[(64 + l15) * 72 + kk * 32 + quad * 8]);
#pragma unroll
        for (int ni = 0; ni < 4; ++ni)
          oacc[ni] = __builtin_amdgcn_mfma_f32_16x16x32_bf16(ap, bv[ni], oacc[ni], 0, 0, 0);
        lacc = __builtin_amdgcn_mfma_f32_16x16x32_bf16(ap, bl, lacc, 0, 0, 0);
      }
    }

    // epilogue: l lives in lanes l15==0 (col 0 of the l-group); broadcast per quad
#pragma unroll
    for (int r = 0; r < 4; ++r) {
      const float lv  = __shfl(lacc[r], lane & 48);   // from lane quad*16
      const float inv = 1.0f / fmaxf(lv, 1e-20f);
      const int qg = qw + quad * 4 + r;
      const size_t rowb = hb + (size_t)qg * 64;
#pragma unroll
      for (int ni = 0; ni < 4; ++ni)
        Q[rowb + ni * 16 + l15] = (__bf16)(oacc[ni][r] * inv);
    }
  }
}

// Final projection: A = attn output (bf16, BHSD gather), W = Wob bf16,
// bias fp32, out fp32 row-major. global_load_lds staging.
__global__ __launch_bounds__(256)
void gemm_o_kernel(const __bf16* __restrict__ A, const __bf16* __restrict__ W,
                   const float* __restrict__ bias, float* __restrict__ out)
{
  __shared__ __attribute__((aligned(16))) __bf16 As[128 * 32];
  __shared__ __attribute__((aligned(16))) __bf16 Ws[128 * 32];
  const int tid  = threadIdx.x;
  const int wave = tid >> 6, lane = tid & 63;
  const int l15  = lane & 15, quad = lane >> 4;
  const int wm   = wave >> 1, wn = wave & 1;
  const int bm   = blockIdx.y * 128;
  const int bn   = blockIdx.x * 128;

  floatx4 acc[4][4];
#pragma unroll
  for (int i = 0; i < 4; ++i)
#pragma unroll
    for (int j = 0; j < 4; ++j) acc[i][j] = (floatx4){0.f, 0.f, 0.f, 0.f};

  const int srow = tid >> 2;
  const int scol = (tid & 3) << 3;
  const __bf16* Wg = W + (size_t)(bn + srow) * 1024 + scol;
  const int bb = bm >> 11;                 // batch
  const int ss = (bm & 2047) + srow;       // seq
  __bf16* AsD = As + tid * 8;
  __bf16* WsD = Ws + tid * 8;

  for (int k0 = 0; k0 < 1024; k0 += 32) {
    const int c = k0 + scol, h = c >> 6, dd = c & 63;  // 8 elems never cross a head
    const __bf16* pa0 = A + (((size_t)(bb * 16 + h) * S_) + ss) * 64 + dd;
    __syncthreads();
    async_cp16(pa0,           AsD);
    async_cp16(pa0 + 64 * 64, AsD + 2048);             // s -> s+64
    async_cp16(Wg + k0,             WsD);
    async_cp16(Wg + k0 + 64 * 1024, WsD + 2048);
    __syncthreads();

    short8 af[4], wf[4];
#pragma unroll
    for (int mi = 0; mi < 4; ++mi)
      af[mi] = *(const short8*)(As + ((wm * 64 + mi * 16 + l15) << 5) + (quad << 3));
#pragma unroll
    for (int ni = 0; ni < 4; ++ni)
      wf[ni] = *(const short8*)(Ws + ((wn * 64 + ni * 16 + l15) << 5) + (quad << 3));
#pragma unroll
    for (int mi = 0; mi < 4; ++mi)
#pragma unroll
      for (int ni = 0; ni < 4; ++ni)
        acc[mi][ni] = __builtin_amdgcn_mfma_f32_16x16x32_bf16(af[mi], wf[ni], acc[mi][ni], 0, 0, 0);
  }

#pragma unroll
  for (int ni = 0; ni < 4; ++ni) {
    const int n = bn + wn * 64 + ni * 16 + l15;
    const float bvb = bias[n];
#pragma unroll
    for (int mi = 0; mi < 4; ++mi) {
      const int m0 = bm + wm * 64 + mi * 16 + quad * 4;
      floatx4 v = acc[mi][ni];
#pragma unroll
      for (int r = 0; r < 4; ++r)
        out[(size_t)(m0 + r) * 1024 + n] = v[r] + bvb;
    }
  }
}

extern "C" void kernel_launch(void* const* d_in, const int* in_sizes, int n_in,
                              void* d_out, int out_size, void* d_ws, size_t ws_size,
                              hipStream_t stream) {
  const float* x  = (const float*)d_in[0];
  const float* Wq = (const float*)d_in[1];
  const float* bq = (const float*)d_in[2];
  const float* Wk = (const float*)d_in[3];
  const float* bk = (const float*)d_in[4];
  const float* Wv = (const float*)d_in[5];
  const float* bv = (const float*)d_in[6];
  const float* Wo = (const float*)d_in[7];
  const float* bo = (const float*)d_in[8];
  // d_in[9] = causal_mask (int32) — causality implemented analytically, unused.

  const size_t BUF = (size_t)B_ * NH_ * S_ * HD_;   // 8388608 elems
  __bf16* ws   = (__bf16*)d_ws;                     // ws usage: ~42 MB
  __bf16* xb   = ws;                                // 8388608  (16.8 MB)
  __bf16* Wcat = ws + 8388608;                      // 3145728  (6 MB)
  __bf16* Wob  = ws + 11534336;                     // 1048576  (2 MB)
  __bf16* Qb   = ws + 12582912;                     // 8388608  (16.8 MB)
  float*  bcat = (float*)(ws + 20971520);           // 3072 fp32 (12 KB)
  __bf16* Kb   = (__bf16*)d_out;                    // d_out reused as K+V^T
  __bf16* Vb   = (__bf16*)d_out + BUF;              // scratch until attn done

  dim3 blk(256);
  cvt_kernel<<<12291, blk, 0, stream>>>(x, Wq, Wk, Wv, Wo, bq, bk, bv,
                                        xb, Wcat, Wob, bcat);
  gemm_qkv_kernel<<<dim3(24, 64), blk, 0, stream>>>(xb, Wcat, bcat, Qb, Kb, Vb);
  attn_kernel<<<dim3(16, 64), blk, 0, stream>>>(Qb, Kb, Vb);
  gemm_o_kernel<<<dim3(8, 64), blk, 0, stream>>>(Qb, Wob, bo, (float*)d_out);
}